// Round 12
// baseline (101.443 us; speedup 1.0000x reference)
//
#include <hip/hip_runtime.h>

#define DEV static __device__ __forceinline__

typedef unsigned short u16;
typedef __bf16 bf16_t;
typedef __bf16 bf16x8 __attribute__((ext_vector_type(8)));
typedef float f32x4 __attribute__((ext_vector_type(4)));
typedef u16 u16x8 __attribute__((ext_vector_type(8)));

static constexpr int Bb = 8;     // batch
static constexpr int Nn = 4096;  // tokens per batch
static constexpr int Dd = 256;   // d
static constexpr int DP = 512;   // d_prime

// ---------------- async global->LDS (16B, wave-uniform LDS base + lane*16) ----------------
DEV void gload16(const void* g, void* l) {
  __builtin_amdgcn_global_load_lds(
      (__attribute__((address_space(1))) void*)(unsigned long long)(g),
      (__attribute__((address_space(3))) void*)(unsigned)(unsigned long long)(l),
      16, 0, 0);
}

DEV u16 f2bf(float x) { bf16_t h = (bf16_t)x; return __builtin_bit_cast(u16, h); }
DEV float bf2f(u16 v) { unsigned u = ((unsigned)v) << 16; return __builtin_bit_cast(float, u); }
DEV float gelu_exact(float x) { return 0.5f * x * (1.0f + erff(x * 0.70710678118654752f)); }

// ------- 128 x (NT*32) tile mainloop, TRIPLE-buffered, counted vmcnt (T3/T4-minimum) ------
template <int NT>
DEV void gemm_tile(const u16* Ag, int lda, const u16* Bg, int ldb,
                   int k0, int ksteps, u16* ldsA, u16* ldsB, f32x4 acc[4][NT]) {
  constexpr int BCH  = NT / 2;
  constexpr int ABUF = 4096;
  constexpr int BBUF = NT * 1024;
  const int tid  = threadIdx.x;
  const int wave = tid >> 6, lane = tid & 63;
  const int wr = wave >> 1, wc = wave & 1;
  const int lr = lane & 15, lk = (lane >> 4) * 8;
  const int srow = lane >> 2;
  const int skb  = (lane & 3) * 8;
  const int ca0 = wave * 2, ca1 = ca0 + 1;
  const size_t ga0 = (size_t)(ca0 * 16 + srow) * lda + skb;
  const size_t ga1 = (size_t)(ca1 * 16 + srow) * lda + skb;
  u16* la0 = ldsA + ca0 * 512; u16* la1 = ldsA + ca1 * 512;
  size_t gb[BCH]; u16* lb[BCH];
#pragma unroll
  for (int i = 0; i < BCH; ++i) {
    const int ch = wave * BCH + i;
    gb[i] = (size_t)(ch * 16 + srow) * ldb + skb;
    lb[i] = ldsB + ch * 512;
  }

  auto STAGE = [&](int kt, int buf) {
    const int kk = k0 + kt * 32;
    gload16(Ag + ga0 + kk, la0 + buf * ABUF);
    gload16(Ag + ga1 + kk, la1 + buf * ABUF);
#pragma unroll
    for (int i = 0; i < BCH; ++i) gload16(Bg + gb[i] + kk, lb[i] + buf * BBUF);
  };

  STAGE(0, 0);
  STAGE(1, 1);
  if constexpr (NT == 2) asm volatile("s_waitcnt vmcnt(3)" ::: "memory");
  else                   asm volatile("s_waitcnt vmcnt(4)" ::: "memory");
  __builtin_amdgcn_s_barrier();
  __builtin_amdgcn_sched_barrier(0);

  int cur = 0;
  for (int kt = 0; kt < ksteps; ++kt) {
    const int sb = (cur + 2 >= 3) ? cur - 1 : cur + 2;
    const bool do_stage = (kt + 2 < ksteps);
    if (do_stage) STAGE(kt + 2, sb);
    const u16* pa = ldsA + cur * ABUF;
    const u16* pb = ldsB + cur * BBUF;
    bf16x8 af[4], bfr[NT];
#pragma unroll
    for (int m = 0; m < 4; ++m)
      af[m] = *(const bf16x8*)(pa + (wr * 64 + m * 16 + lr) * 32 + lk);
#pragma unroll
    for (int n = 0; n < NT; ++n)
      bfr[n] = *(const bf16x8*)(pb + (wc * (NT * 16) + n * 16 + lr) * 32 + lk);
#pragma unroll
    for (int m = 0; m < 4; ++m)
#pragma unroll
      for (int n = 0; n < NT; ++n)
        acc[m][n] = __builtin_amdgcn_mfma_f32_16x16x32_bf16(af[m], bfr[n], acc[m][n], 0, 0, 0);
    if (kt + 1 < ksteps) {
      if (do_stage) {
        if constexpr (NT == 2) asm volatile("s_waitcnt vmcnt(3)" ::: "memory");
        else                   asm volatile("s_waitcnt vmcnt(4)" ::: "memory");
      } else {
        asm volatile("s_waitcnt vmcnt(0)" ::: "memory");
      }
      __builtin_amdgcn_s_barrier();
      __builtin_amdgcn_sched_barrier(0);
    }
    cur = (cur + 1 == 3) ? 0 : cur + 1;
  }
  __builtin_amdgcn_s_barrier();
}

template <int NT>
DEV void acc_zero(f32x4 acc[4][NT]) {
#pragma unroll
  for (int m = 0; m < 4; ++m)
#pragma unroll
    for (int n = 0; n < NT; ++n) {
      f32x4 z = {0.f, 0.f, 0.f, 0.f};
      acc[m][n] = z;
    }
}

// ============ S1 mega-kernel: Xp/XpT/s_part (blocks 0..2047) + Wh prep (2048..2143) ========
__global__ __launch_bounds__(256) void k_s1(const float* __restrict__ X, const float* __restrict__ P,
                                            const float* __restrict__ Wh1, const float* __restrict__ Wh2,
                                            u16* __restrict__ Xp, u16* __restrict__ XpT,
                                            float* __restrict__ s_part,
                                            u16* __restrict__ WhT1, u16* __restrict__ Wbf2) {
  __shared__ u16 lt[64 * 65];
  const int bid = blockIdx.x;
  const int t = threadIdx.x;
  if (bid < 2048) {
    const int b  = bid >> 8;
    const int nt = (bid >> 2) & 63;
    const int dt = bid & 3;
    const int n0 = nt * 64, d0 = dt * 64;
    const int r = t >> 2, c0 = (t & 3) * 16;
    const size_t gbase = ((size_t)(b * Nn + n0 + r)) * Dd + d0 + c0;
    u16x8 lo, hi;
#pragma unroll
    for (int i = 0; i < 4; ++i) {
      float4 xv = *(const float4*)(X + gbase + i * 4);
      float4 pv = *(const float4*)(P + gbase + i * 4);
      u16 a0 = f2bf(xv.x + pv.x), a1 = f2bf(xv.y + pv.y);
      u16 a2 = f2bf(xv.z + pv.z), a3 = f2bf(xv.w + pv.w);
      if (i < 2) { lo[i*4+0]=a0; lo[i*4+1]=a1; lo[i*4+2]=a2; lo[i*4+3]=a3; }
      else       { int q=(i-2)*4; hi[q+0]=a0; hi[q+1]=a1; hi[q+2]=a2; hi[q+3]=a3; }
      lt[r * 65 + c0 + i*4 + 0] = a0; lt[r * 65 + c0 + i*4 + 1] = a1;
      lt[r * 65 + c0 + i*4 + 2] = a2; lt[r * 65 + c0 + i*4 + 3] = a3;
    }
    *(u16x8*)(Xp + gbase)     = lo;
    *(u16x8*)(Xp + gbase + 8) = hi;
    __syncthreads();
    const int dd = t >> 2, nc0 = (t & 3) * 16;
    u16x8 olo, ohi;
    float colsum = 0.f;
#pragma unroll
    for (int i = 0; i < 8; ++i) { olo[i] = lt[(nc0 + i) * 65 + dd]; colsum += bf2f(olo[i]); }
#pragma unroll
    for (int i = 0; i < 8; ++i) { ohi[i] = lt[(nc0 + 8 + i) * 65 + dd]; colsum += bf2f(ohi[i]); }
    const size_t obase = ((size_t)(b * Dd + d0 + dd)) * Nn + n0 + nc0;
    *(u16x8*)(XpT + obase)     = olo;
    *(u16x8*)(XpT + obase + 8) = ohi;
    colsum += __shfl_xor(colsum, 1);
    colsum += __shfl_xor(colsum, 2);
    if ((t & 3) == 0) s_part[(size_t)(b * 64 + nt) * Dd + d0 + dd] = colsum;
  } else if (bid < 2048 + 32) {
    const int wb = bid - 2048;
    const int rt = (wb >> 3) & 3;
    const int ct = wb & 7;
    const int r0 = rt * 64, c0t = ct * 64;
    const int r = t >> 2, c0 = (t & 3) * 16;
    const size_t gbase = (size_t)(r0 + r) * DP + c0t + c0;
#pragma unroll
    for (int i = 0; i < 4; ++i) {
      float4 v = *(const float4*)(Wh1 + gbase + i * 4);
      lt[r * 65 + c0 + i*4 + 0] = f2bf(v.x); lt[r * 65 + c0 + i*4 + 1] = f2bf(v.y);
      lt[r * 65 + c0 + i*4 + 2] = f2bf(v.z); lt[r * 65 + c0 + i*4 + 3] = f2bf(v.w);
    }
    __syncthreads();
    const int pp = t >> 2, dc0 = (t & 3) * 16;
    u16x8 olo, ohi;
#pragma unroll
    for (int i = 0; i < 8; ++i) olo[i] = lt[(dc0 + i) * 65 + pp];
#pragma unroll
    for (int i = 0; i < 8; ++i) ohi[i] = lt[(dc0 + 8 + i) * 65 + pp];
    u16* out = WhT1 + (size_t)(c0t + pp) * Dd + r0 + dc0;
    *(u16x8*)(out)     = olo;
    *(u16x8*)(out + 8) = ohi;
  } else {
    const int idx = ((bid - 2048 - 32) * 256 + t) * 8;
    float4 v0 = *(const float4*)(Wh2 + idx);
    float4 v1 = *(const float4*)(Wh2 + idx + 4);
    u16x8 o;
    o[0]=f2bf(v0.x); o[1]=f2bf(v0.y); o[2]=f2bf(v0.z); o[3]=f2bf(v0.w);
    o[4]=f2bf(v1.x); o[5]=f2bf(v1.y); o[6]=f2bf(v1.z); o[7]=f2bf(v1.w);
    *(u16x8*)(Wbf2 + idx) = o;
  }
}

// ====== k_gram: G_part[kc][b][256][256] (bf16) = XpT[b] @ XpT[b]^T K-slice, plain stores ===
__global__ __launch_bounds__(256) void k_gram(const u16* __restrict__ XpT, u16* __restrict__ G_part) {
  __shared__ __align__(16) u16 ldsA[3 * 128 * 32];
  __shared__ __align__(16) u16 ldsB[3 * 64 * 32];
  const int bid0 = blockIdx.x;
  const int bid = (bid0 & 7) * 64 + (bid0 >> 3);   // bijective: 512 = 8 XCD * 64
  const int kc = bid & 7;
  const int tn = (bid >> 3) & 3;
  const int tm = (bid >> 5) & 1;
  const int b  = bid >> 6;
  const u16* Ag = XpT + (size_t)(b * Dd + tm * 128) * Nn;
  const u16* Bg = XpT + (size_t)(b * Dd + tn * 64) * Nn;
  f32x4 acc[4][2];
  acc_zero<2>(acc);
  gemm_tile<2>(Ag, Nn, Bg, Nn, kc * 512, 16, ldsA, ldsB, acc);
  const int tid = threadIdx.x, wave = tid >> 6, lane = tid & 63;
  const int wr = wave >> 1, wc = wave & 1, lr = lane & 15, lq = lane >> 4;
  u16* base = G_part + (size_t)kc * (Bb * Dd * Dd) + (size_t)(b * Dd + tm * 128) * Dd + tn * 64;
#pragma unroll
  for (int m = 0; m < 4; ++m)
#pragma unroll
    for (int n = 0; n < 2; ++n)
#pragma unroll
      for (int j = 0; j < 4; ++j)
        base[(size_t)(wr * 64 + m * 16 + lq * 4 + j) * Dd + wc * 32 + n * 16 + lr] =
            f2bf(acc[m][n][j]);
}

// ==== k_gsum: blocks 0..7 -> s reduce ; blocks 8..263 -> Gb = bf16(sum of 8 bf16 slabs) ====
__global__ __launch_bounds__(256) void k_gsum(const u16* __restrict__ G_part,
                                              const float* __restrict__ s_part,
                                              u16* __restrict__ Gb, float* __restrict__ s) {
  const int bid = blockIdx.x;
  const int t = threadIdx.x;
  if (bid < 8) {
    const int b = bid, d = t;
    float sum = 0.f;
#pragma unroll 8
    for (int nt = 0; nt < 64; ++nt) sum += s_part[(size_t)(b * 64 + nt) * Dd + d];
    s[b * Dd + d] = sum;
  } else {
    const int e = ((bid - 8) * 256 + t) * 8;
    float a[8] = {0.f,0.f,0.f,0.f,0.f,0.f,0.f,0.f};
#pragma unroll
    for (int k = 0; k < 8; ++k) {
      u16x8 v = *(const u16x8*)(G_part + (size_t)k * (Bb * Dd * Dd) + e);
#pragma unroll
      for (int i = 0; i < 8; ++i) a[i] += bf2f(v[i]);
    }
    u16x8 o;
#pragma unroll
    for (int i = 0; i < 8; ++i) o[i] = f2bf(a[i]);
    *(u16x8*)(Gb + e) = o;
  }
}

// ==== k_pmATh: per block (b, d-half, kd-half): loop p-chunks {pmAT -> gelu -> act in LDS ->
//      h-MFMA from act}; HT written at end; c via in-register accumulation (km==0, plain store).
//      A (gelu'd) never touches global memory. 32 blocks.
__global__ __launch_bounds__(256) void k_pmATh(
    const u16* __restrict__ WhT1, const u16* __restrict__ Gb,
    const float* __restrict__ bh1, const float* __restrict__ s,
    const float* __restrict__ bh2, const u16* __restrict__ Wbf2,
    float* __restrict__ c, u16* __restrict__ HT) {
  __shared__ __align__(16) u16 smem[24576];      // 48 KB
  u16* ldsA = smem;                               // gemm_tile<4>: 3*4096 u16
  u16* ldsB = smem + 12288;                       // 3*4096 u16
  u16* act  = smem;                               // [128 d][136] (34.8 KB), aliases gemm bufs
  u16* hA   = smem + 17920;                       // 8 KB Wbf2 staging (beyond act, within 48K)
  const int bid = blockIdx.x;      // 8b * 2tn * 2km
  const int km = bid & 1;
  const int tn = (bid >> 1) & 1;
  const int b  = bid >> 2;
  const int d0 = tn * 128, k0 = km * 128;
  const int tid = threadIdx.x;
  const int wave = tid >> 6, lane = tid & 63;
  const int wr = wave >> 1, wc = wave & 1, lr = lane & 15, lq = lane >> 4;
  const int lk = lq * 8;
  const int srow = lane >> 2, skb = (lane & 3) * 8;
  const int ca0 = wave * 2, ca1 = ca0 + 1;
  const int ccol = tid >> 1, chalf = tid & 1;

  f32x4 acch[4][4];
  acc_zero<4>(acch);
  float csum = 0.f;

  for (int tm = 0; tm < 4; ++tm) {
    const int p0 = tm * 128;
    // ---- pmAT: accA = WhT1[p0:+128] x Gb[b][d0:+128]^T over K=256 ----
    f32x4 accA[4][4];
    acc_zero<4>(accA);
    gemm_tile<4>(WhT1 + (size_t)p0 * Dd, Dd, Gb + (size_t)(b * Dd + d0) * Dd, Dd,
                 0, Dd / 32, ldsA, ldsB, accA);
    // ---- act[d][p] = bf16(gelu(accA + bh1 * s)) ----
#pragma unroll
    for (int n = 0; n < 4; ++n) {
      const int col = wc * 64 + n * 16 + lr;              // d local
      const float sv = s[b * Dd + d0 + col];
#pragma unroll
      for (int m = 0; m < 4; ++m)
#pragma unroll
        for (int j = 0; j < 4; ++j) {
          const int row = wr * 64 + m * 16 + lq * 4 + j;  // p local
          act[col * 136 + row] = f2bf(gelu_exact(accA[m][n][j] + bh1[p0 + row] * sv));
        }
    }
    __syncthreads();
    // ---- c partial: csum += bh2 . act (km==0 blocks only; accumulated across tm) ----
    if (km == 0) {
#pragma unroll
      for (int q = 0; q < 8; ++q) {
        u16x8 av = *(const u16x8*)(act + ccol * 136 + chalf * 64 + q * 8);
#pragma unroll
        for (int i = 0; i < 8; ++i) csum += bh2[p0 + chalf * 64 + q * 8 + i] * bf2f(av[i]);
      }
    }
    // ---- h partial: acch += Wbf2[k0:+128][p-chunk] x act (K = 128, 4 ksteps) ----
    for (int kt = 0; kt < 4; ++kt) {
      gload16(Wbf2 + (size_t)(k0 + ca0 * 16 + srow) * DP + p0 + kt * 32 + skb, hA + ca0 * 512);
      gload16(Wbf2 + (size_t)(k0 + ca1 * 16 + srow) * DP + p0 + kt * 32 + skb, hA + ca1 * 512);
      asm volatile("s_waitcnt vmcnt(0)" ::: "memory");
      __syncthreads();
      bf16x8 af[4], bfr[4];
#pragma unroll
      for (int m = 0; m < 4; ++m)
        af[m] = *(const bf16x8*)(hA + (wr * 64 + m * 16 + lr) * 32 + lk);
#pragma unroll
      for (int n = 0; n < 4; ++n)
        bfr[n] = *(const bf16x8*)(act + (wc * 64 + n * 16 + lr) * 136 + kt * 32 + lk);
#pragma unroll
      for (int m = 0; m < 4; ++m)
#pragma unroll
        for (int n = 0; n < 4; ++n)
          acch[m][n] = __builtin_amdgcn_mfma_f32_16x16x32_bf16(af[m], bfr[n], acch[m][n], 0, 0, 0);
      __syncthreads();
    }
  }

  if (km == 0) {
    csum += __shfl_xor(csum, 1);
    if (chalf == 0) c[b * Dd + d0 + ccol] = csum;
  }

  // ---- write HT[b][d0:+128][k0:+128] from acch via LDS relayout ----
  u16* ct = smem;
#pragma unroll
  for (int n = 0; n < 4; ++n) {
    const int col = wc * 64 + n * 16 + lr;                // d_out local
#pragma unroll
    for (int m = 0; m < 4; ++m)
#pragma unroll
      for (int j = 0; j < 4; ++j)
        ct[col * 136 + wr * 64 + m * 16 + lq * 4 + j] = f2bf(acch[m][n][j]);
  }
  __syncthreads();
#pragma unroll
  for (int it = 0; it < 8; ++it) {
    const int id = tid + it * 256;
    const int dl = id >> 4, ch = id & 15;
    *(u16x8*)(HT + (size_t)(b * Dd + d0 + dl) * Dd + k0 + ch * 8) =
        *(const u16x8*)(ct + dl * 136 + ch * 8);
  }
}

// -------- kernel: Y[b][n][d] = Xp[b] @ H[b] + c[b][d]  (1024 blocks of 128x64, NT=2) ------
__global__ __launch_bounds__(256) void k_y(const u16* __restrict__ Xp, const u16* __restrict__ HT,
                                           const float* __restrict__ c, float* __restrict__ Y) {
  __shared__ __align__(16) u16 ldsA[3 * 128 * 32];
  __shared__ __align__(16) u16 ldsB[3 * 64 * 32];
  const int bid0 = blockIdx.x;
  const int bid = (bid0 & 7) * 128 + (bid0 >> 3);   // bijective: 1024 = 8 XCD * 128
  const int b  = bid >> 7;
  const int tm = (bid >> 2) & 31;
  const int tn = bid & 3;
  const u16* Ag = Xp + (size_t)(b * Nn + tm * 128) * Dd;
  const u16* Bg = HT + (size_t)(b * Dd + tn * 64) * Dd;
  f32x4 acc[4][2];
  acc_zero<2>(acc);
  gemm_tile<2>(Ag, Dd, Bg, Dd, 0, Dd / 32, ldsA, ldsB, acc);
  const int tid = threadIdx.x, wave = tid >> 6, lane = tid & 63;
  const int wr = wave >> 1, wc = wave & 1, lr = lane & 15, lq = lane >> 4;
  float* base = Y + (size_t)(b * Nn + tm * 128) * Dd + tn * 64;
#pragma unroll
  for (int n = 0; n < 2; ++n) {
    const int col = wc * 32 + n * 16 + lr;
    const float cv = c[b * Dd + tn * 64 + col];
#pragma unroll
    for (int m = 0; m < 4; ++m)
#pragma unroll
      for (int j = 0; j < 4; ++j)
        base[(size_t)(wr * 64 + m * 16 + lq * 4 + j) * Dd + col] = acc[m][n][j] + cv;
  }
}

// ---------------- launcher ----------------
extern "C" void kernel_launch(void* const* d_in, const int* in_sizes, int n_in,
                              void* d_out, int out_size, void* d_ws, size_t ws_size,
                              hipStream_t stream) {
  const float* X   = (const float*)d_in[0];
  const float* P   = (const float*)d_in[1];
  const float* Wh1 = (const float*)d_in[2];
  const float* bh1 = (const float*)d_in[3];
  const float* Wh2 = (const float*)d_in[4];
  const float* bh2 = (const float*)d_in[5];
  float* Y = (float*)d_out;
  char* ws = (char*)d_ws;

  // workspace layout (bytes)
  u16*   Xp     = (u16*)(ws);                     // 16,777,216
  u16*   XpT    = (u16*)(ws + 16777216);          // 16,777,216
  u16*   WhT1   = (u16*)(ws + 33554432);          //    262,144
  u16*   Wbf2   = (u16*)(ws + 33816576);          //    262,144
  u16*   G_part = (u16*)(ws + 34078720);          //  8,388,608  (8 bf16 split-K slabs)
  float* s_part = (float*)(ws + 42467328);        //    524,288
  float* s      = (float*)(ws + 42991616);        //      8,192
  float* c      = (float*)(ws + 42999808);        //      8,192
  u16*   Gb     = (u16*)(ws + 43008000);          //  1,048,576
  u16*   HT     = (u16*)(ws + 44056576);          //  1,048,576
  const size_t WS_NEED = 45105152;
  if (ws_size < WS_NEED) return;

  k_s1   <<<2144, 256, 0, stream>>>(X, P, Wh1, Wh2, Xp, XpT, s_part, WhT1, Wbf2);
  k_gram <<<512,  256, 0, stream>>>(XpT, G_part);
  k_gsum <<<264,  256, 0, stream>>>(G_part, s_part, Gb, s);
  k_pmATh<<<32,   256, 0, stream>>>(WhT1, Gb, bh1, s, bh2, Wbf2, c, HT);
  k_y    <<<1024, 256, 0, stream>>>(Xp, HT, c, Y);
}